// Round 9
// baseline (10241.714 us; speedup 1.0000x reference)
//
#include <hip/hip_runtime.h>
#include <hip/hip_bf16.h>

#define B_ 128
#define T_ 512
#define E_ 256
#define H_ 1024
#define G_ 4096           // 4*H
#define KTOT 1280         // E + H
#define WSTR 1290         // Wlds column stride (bank-conflict-free)
// s_getreg imm: size-1=31 <<11 | offset=0 <<6 | id=20 (HW_REG_XCC_ID)
#define XCC_GETREG_IMM ((31u << 11) | 20u)

typedef _Float16 f16x8 __attribute__((ext_vector_type(8)));
typedef float f32x4 __attribute__((ext_vector_type(4)));

// ---------------- JAX threefry2x32 (exact) ----------------
__device__ __forceinline__ void threefry2x32(unsigned k0, unsigned k1,
                                             unsigned x0, unsigned x1,
                                             unsigned& o0, unsigned& o1) {
  unsigned k2 = k0 ^ k1 ^ 0x1BD11BDAu;
  unsigned v0 = x0 + k0, v1 = x1 + k1;
#define RND(r) { v0 += v1; v1 = (v1 << (r)) | (v1 >> (32 - (r))); v1 ^= v0; }
  RND(13) RND(15) RND(26) RND(6)   v0 += k1; v1 += k2 + 1u;
  RND(17) RND(29) RND(16) RND(24)  v0 += k2; v1 += k0 + 2u;
  RND(13) RND(15) RND(26) RND(6)   v0 += k0; v1 += k1 + 3u;
  RND(17) RND(29) RND(16) RND(24)  v0 += k1; v1 += k2 + 4u;
  RND(13) RND(15) RND(26) RND(6)   v0 += k2; v1 += k0 + 5u;
#undef RND
  o0 = v0; o1 = v1;
}

// JAX threefry_partitionable (default since 0.4.30), bit_width=32:
// bits(i) = b1 ^ b2 with (b1,b2) = threefry2x32(key, hi32(i)=0, lo32(i)=i)
__device__ __forceinline__ bool jax_keep(unsigned k1, unsigned i) {
  unsigned o0, o1;
  threefry2x32(0u, k1, 0u, i, o0, o1);
  unsigned bits = o0 ^ o1;
  float u = __uint_as_float((bits >> 9) | 0x3F800000u) - 1.0f;
  return u < 0.8f;
}

// ---------------- embedding + input dropout + mask ----------------
__global__ void embed_kernel(const int* __restrict__ tokens,
                             const int* __restrict__ lengths,
                             const float* __restrict__ emb,
                             _Float16* __restrict__ x) {
  unsigned i = blockIdx.x * 256u + threadIdx.x;
  if (i >= (unsigned)(B_ * T_ * E_)) return;
  int e = (int)(i & (E_ - 1));
  int t = (int)((i >> 8) & (T_ - 1));
  int b = (int)(i >> 17);
  int tok = tokens[b * T_ + t];
  float v = emb[tok * E_ + e];
  bool m = t < lengths[b];
  float xv = (m && jax_keep(1u, i)) ? (v * 1.25f) : 0.0f;
  x[i] = (_Float16)xv;
}

// ---------------- fast gate math ----------------
__device__ __forceinline__ float sigm(float v) { return 1.0f / (1.0f + __expf(-v)); }
__device__ __forceinline__ float tanh_fast(float v) {
  float c = fminf(fmaxf(v, -10.f), 10.f);
  float e = __expf(2.0f * c);
  return (e - 1.0f) / (e + 1.0f);
}

// L1-bypass, L2-CACHEABLE 16B load (sc0 only). Post-inv the XCD L2 is clean,
// so 32 wgs/XCD share one L3 fetch of each h line.
#define HLD(dst, base, OFF) \
  asm volatile("global_load_dwordx4 %0, %1, off offset:" OFF " sc0" \
               : "=v"(dst) : "v"(base))

// ---------------- persistent bidirectional LSTM ----------------
// sync layout (words): [0..255] flags  [1024..1031] roster  [2048 + 32*xcd] go
__global__ __launch_bounds__(512) void lstm_kernel(
    const float* __restrict__ WxF, const float* __restrict__ WhF, const float* __restrict__ bF,
    const float* __restrict__ WxB, const float* __restrict__ WhB, const float* __restrict__ bB,
    const int* __restrict__ lengths,
    const _Float16* __restrict__ x,    // [B][T][E]
    _Float16* __restrict__ hbuf,       // [dir][2][B][H]
    unsigned* __restrict__ sync,       // memset 0 per launch
    float* __restrict__ out)           // [B][T][H]
{
  __shared__ _Float16 Wlds[32][WSTR];  // [col][k]
  __shared__ float zlds[128][36];
  __shared__ float bias_s[32];
  __shared__ int len_s[128];
  __shared__ unsigned master_slot;

  const int wg   = blockIdx.x;
  const int dir  = wg & 1;
  const int cb   = wg >> 1;           // h-column block: cols [cb*8, cb*8+8)
  const int tid  = (int)threadIdx.x;
  const int lane = tid & 63;
  const int wv   = tid >> 6;          // wave 0..7

  // actual XCD of this CU (hardware register; no mapping assumption)
  const unsigned xcc = __builtin_amdgcn_s_getreg(XCC_GETREG_IMM) & 7u;
  unsigned* flags = sync;
  unsigned* goPtr = sync + 2048 + xcc * 32;

  if (tid == 0) master_slot = atomicAdd(sync + 1024 + xcc, 1u);

  const float* Wx = dir ? WxB : WxF;
  const float* Wh = dir ? WhB : WhF;
  const float* bias = dir ? bB : bF;
  _Float16* hb = hbuf + (size_t)dir * (2 * B_ * H_);

  // load W slice (f32 -> f16) : lds col c = gate(c>>3)*1024 + cb*8 + (c&7)
  for (int idx = tid; idx < KTOT * 32; idx += 512) {
    int k = idx >> 5, c = idx & 31;
    int wcol = ((c >> 3) << 10) + cb * 8 + (c & 7);
    float v = (k < E_) ? Wx[k * G_ + wcol] : Wh[(k - E_) * G_ + wcol];
    Wlds[c][k] = (_Float16)v;
  }
  if (tid < 32)  bias_s[tid] = bias[((tid >> 3) << 10) + cb * 8 + (tid & 7)];
  if (tid < B_)  len_s[tid] = lengths[tid];
  __syncthreads();
  const bool is_master = (master_slot == 0u);   // one master per (non-empty) XCD

  // gate-phase mapping: thread -> (batch gb, h-sub-cols gj, gj+1)
  const int gb = tid >> 2;
  const int gj = (tid & 3) * 2;
  float creg0 = 0.f, creg1 = 0.f, hreg0 = 0.f, hreg1 = 0.f;

  // GEMM mapping
  const int mrow = (wv << 4) + (lane & 15);
  const int ksub = (lane >> 4) << 3;
  const int c0   = lane & 15;
  const _Float16* xbase = x + (size_t)mrow * T_ * E_;
  const _Float16* w0 = &Wlds[c0][0];
  const _Float16* w1 = &Wlds[16 + c0][0];

  int cur = 0;
#pragma unroll 1
  for (int s = 0; s < T_; ++s) {
    const int t = dir ? (T_ - 1 - s) : s;
    float* op = out + ((size_t)gb * T_ + t) * H_ + cb * 8 + gj;

    // x-part GEMM: no dependency on h(s-1), runs before any wait
    f32x4 acc0 = {0.f, 0.f, 0.f, 0.f}, acc1 = {0.f, 0.f, 0.f, 0.f};
    {
      const _Float16* xr = xbase + t * E_ + ksub;
#pragma unroll
      for (int kk = 0; kk < 8; ++kk) {       // k = 0..255
        f16x8 a  = *(const f16x8*)(xr + kk * 32);
        f16x8 q0 = *(const f16x8*)(w0 + ksub + kk * 32);
        f16x8 q1 = *(const f16x8*)(w1 + ksub + kk * 32);
        acc0 = __builtin_amdgcn_mfma_f32_16x16x32_f16(a, q0, acc0, 0, 0, 0);
        acc1 = __builtin_amdgcn_mfma_f32_16x16x32_f16(a, q1, acc1, 0, 0, 0);
      }
    }

    float oy0 = 0.f, oy1 = 0.f;
    if (s > 0) {
      const unsigned tgt = (unsigned)s;
      // master: wait all 256 producer flags at L3, ONE buffer_inv, release go
      if (is_master && wv == 0) {
        while (1) {
          unsigned a = __hip_atomic_load(flags + lane,       __ATOMIC_RELAXED, __HIP_MEMORY_SCOPE_SYSTEM);
          unsigned b = __hip_atomic_load(flags + 64 + lane,  __ATOMIC_RELAXED, __HIP_MEMORY_SCOPE_SYSTEM);
          unsigned c = __hip_atomic_load(flags + 128 + lane, __ATOMIC_RELAXED, __HIP_MEMORY_SCOPE_SYSTEM);
          unsigned d = __hip_atomic_load(flags + 192 + lane, __ATOMIC_RELAXED, __HIP_MEMORY_SCOPE_SYSTEM);
          if (__all(a >= tgt && b >= tgt && c >= tgt && d >= tgt)) break;
          __builtin_amdgcn_s_sleep(1);
        }
        __builtin_amdgcn_fence(__ATOMIC_ACQUIRE, "agent");   // inv L1 + this XCD's L2
        if (lane == 0)
          __hip_atomic_store(goPtr, tgt, __ATOMIC_RELAXED, __HIP_MEMORY_SCOPE_AGENT);
      }
      // members (and master's other waves): cheap XCD-local L2 poll
      while (1) {
        unsigned g = 0;
        if (lane == 0) g = __hip_atomic_load(goPtr, __ATOMIC_RELAXED, __HIP_MEMORY_SCOPE_AGENT);
        g = __shfl(g, 0);
        if (g >= tgt) break;
        __builtin_amdgcn_s_sleep(2);
      }

      // out-RMW operands (post-midpoint; fresh at L3 since other dir's s==255
      // release, first touch on this XCD is after the s>=256 inv)
      if (s >= 256) { oy0 = op[0]; oy1 = op[1]; }

      // h-part GEMM: sc0 loads -> shared XCD-L2 copy of h
      const _Float16* hr = hb + (size_t)cur * (B_ * H_) + mrow * H_ + ksub;
      f16x8 ha[32];
      HLD(ha[0],  hr, "0");    HLD(ha[1],  hr, "64");   HLD(ha[2],  hr, "128");  HLD(ha[3],  hr, "192");
      HLD(ha[4],  hr, "256");  HLD(ha[5],  hr, "320");  HLD(ha[6],  hr, "384");  HLD(ha[7],  hr, "448");
      HLD(ha[8],  hr, "512");  HLD(ha[9],  hr, "576");  HLD(ha[10], hr, "640");  HLD(ha[11], hr, "704");
      HLD(ha[12], hr, "768");  HLD(ha[13], hr, "832");  HLD(ha[14], hr, "896");  HLD(ha[15], hr, "960");
      HLD(ha[16], hr, "1024"); HLD(ha[17], hr, "1088"); HLD(ha[18], hr, "1152"); HLD(ha[19], hr, "1216");
      HLD(ha[20], hr, "1280"); HLD(ha[21], hr, "1344"); HLD(ha[22], hr, "1408"); HLD(ha[23], hr, "1472");
      HLD(ha[24], hr, "1536"); HLD(ha[25], hr, "1600"); HLD(ha[26], hr, "1664"); HLD(ha[27], hr, "1728");
      HLD(ha[28], hr, "1792"); HLD(ha[29], hr, "1856"); HLD(ha[30], hr, "1920"); HLD(ha[31], hr, "1984");

      asm volatile("s_waitcnt vmcnt(16)" ::: "memory");  // >= chunk A landed
      __builtin_amdgcn_sched_barrier(0);
#pragma unroll
      for (int kk = 0; kk < 16; ++kk) {
        f16x8 q0 = *(const f16x8*)(w0 + E_ + ksub + kk * 32);
        f16x8 q1 = *(const f16x8*)(w1 + E_ + ksub + kk * 32);
        acc0 = __builtin_amdgcn_mfma_f32_16x16x32_f16(ha[kk], q0, acc0, 0, 0, 0);
        acc1 = __builtin_amdgcn_mfma_f32_16x16x32_f16(ha[kk], q1, acc1, 0, 0, 0);
      }
      asm volatile("s_waitcnt vmcnt(0)" ::: "memory");   // all landed
      __builtin_amdgcn_sched_barrier(0);
#pragma unroll
      for (int kk = 16; kk < 32; ++kk) {
        f16x8 q0 = *(const f16x8*)(w0 + E_ + ksub + kk * 32);
        f16x8 q1 = *(const f16x8*)(w1 + E_ + ksub + kk * 32);
        acc0 = __builtin_amdgcn_mfma_f32_16x16x32_f16(ha[kk], q0, acc0, 0, 0, 0);
        acc1 = __builtin_amdgcn_mfma_f32_16x16x32_f16(ha[kk], q1, acc1, 0, 0, 0);
      }
    }

    // dump z tile to wave-private zlds rows (same-wave write/read, no barrier)
    {
      int r0 = (wv << 4) + ((lane >> 4) << 2);
#pragma unroll
      for (int r = 0; r < 4; ++r) {
        zlds[r0 + r][c0]      = acc0[r];
        zlds[r0 + r][16 + c0] = acc1[r];
      }
    }
    {
      bool m = t < len_s[gb];
      float zi0 = zlds[gb][gj]      + bias_s[gj];
      float zf0 = zlds[gb][8 + gj]  + bias_s[8 + gj];
      float zg0 = zlds[gb][16 + gj] + bias_s[16 + gj];
      float zo0 = zlds[gb][24 + gj] + bias_s[24 + gj];
      float zi1 = zlds[gb][gj + 1]  + bias_s[gj + 1];
      float zf1 = zlds[gb][9 + gj]  + bias_s[9 + gj];
      float zg1 = zlds[gb][17 + gj] + bias_s[17 + gj];
      float zo1 = zlds[gb][25 + gj] + bias_s[25 + gj];

      float cn0 = sigm(zf0) * creg0 + sigm(zi0) * tanh_fast(zg0);
      float hn0 = sigm(zo0) * tanh_fast(cn0);
      float cn1 = sigm(zf1) * creg1 + sigm(zi1) * tanh_fast(zg1);
      float hn1 = sigm(zo1) * tanh_fast(cn1);
      if (m) { creg0 = cn0; hreg0 = hn0; creg1 = cn1; hreg1 = hn1; }
      float y0 = m ? hn0 : 0.f;
      float y1 = m ? hn1 : 0.f;

      // h write-through to L3 (coherence point for all XCDs)
      _Float16* hw = hb + (size_t)(cur ^ 1) * (B_ * H_) + gb * H_ + cb * 8 + gj;
      union { _Float16 h2[2]; unsigned u; } pk;
      pk.h2[0] = (_Float16)hreg0; pk.h2[1] = (_Float16)hreg1;
      __hip_atomic_store((unsigned*)hw, pk.u, __ATOMIC_RELAXED, __HIP_MEMORY_SCOPE_SYSTEM);

      if (s < 256) {                         // first writer: raw partial sum
        op[0] = y0; op[1] = y1;
      } else {                               // second writer: add + fused dropout
        unsigned i0 = (((unsigned)gb * T_ + (unsigned)t) << 10) + (unsigned)(cb * 8 + gj);
        float f0 = oy0 + y0, f1 = oy1 + y1;
        op[0] = jax_keep(2u, i0)      ? f0 * 1.25f : 0.f;
        op[1] = jax_keep(2u, i0 + 1u) ? f1 * 1.25f : 0.f;
      }
    }

    // publish: all waves' stores drained (vmcnt before s_barrier), one flag.
    // s==255 uses RELEASE (buffer_wbl2) so out partials reach L3.
    if (s < T_ - 1) {
      __syncthreads();
      if (tid == 0) {
        if (s == 255)
          __hip_atomic_store(flags + dir * 128 + cb, 256u, __ATOMIC_RELEASE, __HIP_MEMORY_SCOPE_SYSTEM);
        else
          __hip_atomic_store(flags + dir * 128 + cb, (unsigned)(s + 1), __ATOMIC_RELAXED, __HIP_MEMORY_SCOPE_SYSTEM);
      }
    }
    cur ^= 1;
  }
}

extern "C" void kernel_launch(void* const* d_in, const int* in_sizes, int n_in,
                              void* d_out, int out_size, void* d_ws, size_t ws_size,
                              hipStream_t stream) {
  (void)in_sizes; (void)n_in; (void)out_size; (void)ws_size;
  const int*   tokens  = (const int*)d_in[0];
  const int*   lengths = (const int*)d_in[1];
  const float* emb     = (const float*)d_in[2];
  const float* WxF     = (const float*)d_in[3];
  const float* WhF     = (const float*)d_in[4];
  const float* bF      = (const float*)d_in[5];
  const float* WxB     = (const float*)d_in[6];
  const float* WhB     = (const float*)d_in[7];
  const float* bB      = (const float*)d_in[8];
  float* out = (float*)d_out;

  _Float16* x     = (_Float16*)d_ws;                                     // 32 MB
  _Float16* hbuf  = (_Float16*)((char*)d_ws + (size_t)B_ * T_ * E_ * 2); // 1 MB
  unsigned* sync  = (unsigned*)((char*)d_ws + 34603008);                 // 16 KB

  hipMemsetAsync(sync, 0, 16384, stream);

  embed_kernel<<<(B_ * T_ * E_ + 255) / 256, 256, 0, stream>>>(tokens, lengths, emb, x);

  void* args[] = { (void*)&WxF, (void*)&WhF, (void*)&bF,
                   (void*)&WxB, (void*)&WhB, (void*)&bB,
                   (void*)&lengths, (void*)&x, (void*)&hbuf, (void*)&sync, (void*)&out };
  hipLaunchCooperativeKernel((const void*)lstm_kernel, dim3(256), dim3(512),
                             args, 0, stream);
}

// Round 10
// 9568.346 us; speedup vs baseline: 1.0704x; 1.0704x over previous
//
#include <hip/hip_runtime.h>
#include <hip/hip_bf16.h>

#define B_ 128
#define T_ 512
#define E_ 256
#define H_ 1024
#define G_ 4096           // 4*H
#define KTOT 1280         // E + H
#define WSTR 1290         // Wlds column stride (bank-conflict-free: 645 mod 32 = 5, odd)

typedef _Float16 f16x8 __attribute__((ext_vector_type(8)));
typedef float f32x4 __attribute__((ext_vector_type(4)));

// ---------------- JAX threefry2x32 (exact) ----------------
__device__ __forceinline__ void threefry2x32(unsigned k0, unsigned k1,
                                             unsigned x0, unsigned x1,
                                             unsigned& o0, unsigned& o1) {
  unsigned k2 = k0 ^ k1 ^ 0x1BD11BDAu;
  unsigned v0 = x0 + k0, v1 = x1 + k1;
#define RND(r) { v0 += v1; v1 = (v1 << (r)) | (v1 >> (32 - (r))); v1 ^= v0; }
  RND(13) RND(15) RND(26) RND(6)   v0 += k1; v1 += k2 + 1u;
  RND(17) RND(29) RND(16) RND(24)  v0 += k2; v1 += k0 + 2u;
  RND(13) RND(15) RND(26) RND(6)   v0 += k0; v1 += k1 + 3u;
  RND(17) RND(29) RND(16) RND(24)  v0 += k1; v1 += k2 + 4u;
  RND(13) RND(15) RND(26) RND(6)   v0 += k2; v1 += k0 + 5u;
#undef RND
  o0 = v0; o1 = v1;
}

// JAX threefry_partitionable (default since 0.4.30), bit_width=32:
// bits(i) = b1 ^ b2 with (b1,b2) = threefry2x32(key, hi32(i)=0, lo32(i)=i)
__device__ __forceinline__ bool jax_keep(unsigned k1, unsigned i) {
  unsigned o0, o1;
  threefry2x32(0u, k1, 0u, i, o0, o1);
  unsigned bits = o0 ^ o1;
  float u = __uint_as_float((bits >> 9) | 0x3F800000u) - 1.0f;
  return u < 0.8f;
}

// ---------------- embedding + input dropout + mask ----------------
__global__ void embed_kernel(const int* __restrict__ tokens,
                             const int* __restrict__ lengths,
                             const float* __restrict__ emb,
                             _Float16* __restrict__ x) {
  unsigned i = blockIdx.x * 256u + threadIdx.x;
  if (i >= (unsigned)(B_ * T_ * E_)) return;
  int e = (int)(i & (E_ - 1));
  int t = (int)((i >> 8) & (T_ - 1));
  int b = (int)(i >> 17);
  int tok = tokens[b * T_ + t];
  float v = emb[tok * E_ + e];
  bool m = t < lengths[b];
  float xv = (m && jax_keep(1u, i)) ? (v * 1.25f) : 0.0f;
  x[i] = (_Float16)xv;
}

// ---------------- fast gate math ----------------
__device__ __forceinline__ float sigm(float v) { return 1.0f / (1.0f + __expf(-v)); }
__device__ __forceinline__ float tanh_fast(float v) {
  float c = fminf(fmaxf(v, -10.f), 10.f);
  float e = __expf(2.0f * c);
  return (e - 1.0f) / (e + 1.0f);
}

// L2-bypass 16B load (sc0 sc1 -> reads at the L3 coherence point)
#define HLD(dst, base, OFF) \
  asm volatile("global_load_dwordx4 %0, %1, off offset:" OFF " sc0 sc1" \
               : "=v"(dst) : "v"(base))

// Hot-poll heater: ~32 dependent FMAs per poll iteration keeps VALU busy so
// the SMU holds SCLK at boost (idle spin-loops downclock the chip ~5x).
#define HEAT() do { \
    _Pragma("unroll") \
    for (int z_ = 0; z_ < 16; ++z_) { \
      hx0 = __builtin_fmaf(hx0, 1.000001f, 1.0f); \
      hx1 = __builtin_fmaf(hx1, 0.999999f, 1.0f); \
    } \
    asm volatile("" :: "v"(hx0), "v"(hx1)); \
  } while (0)

// ---------------- persistent bidirectional LSTM ----------------
// Structure: 256 wgs (dir = wg&1, col-block cb = wg>>1). Within a wg the 8
// waves are fully decoupled: wave w owns batch rows [16w,16w+16) end-to-end.
// NO __syncthreads in the T loop; sync is 8 independent 128-wide per-row-group
// flag pipelines: flags[dir][wave][cb], published after the wave's vmcnt drain.
__global__ __launch_bounds__(512) void lstm_kernel(
    const float* __restrict__ WxF, const float* __restrict__ WhF, const float* __restrict__ bF,
    const float* __restrict__ WxB, const float* __restrict__ WhB, const float* __restrict__ bB,
    const int* __restrict__ lengths,
    const _Float16* __restrict__ x,    // [B][T][E]
    _Float16* __restrict__ hbuf,       // [dir][2][B][H]
    unsigned* __restrict__ flags,      // [2][8][128] per-(wg,wave) step counters (memset 0)
    float* __restrict__ out)           // [B][T][H]
{
  __shared__ _Float16 Wlds[32][WSTR];  // [col][k]
  __shared__ float zlds[128][36];
  __shared__ float bias_s[32];
  __shared__ int len_s[128];

  const int wg   = blockIdx.x;
  const int dir  = wg & 1;            // even wgs = fwd, odd = bwd (XCD split)
  const int cb   = wg >> 1;           // h-column block: cols [cb*8, cb*8+8)
  const int tid  = (int)threadIdx.x;
  const int lane = tid & 63;
  const int wv   = tid >> 6;          // wave 0..7 == batch-row group

  unsigned* fl_own = flags + dir * 1024 + wv * 128;
  unsigned* fl_oth = flags + (dir ^ 1) * 1024 + wv * 128;

  const float* Wx = dir ? WxB : WxF;
  const float* Wh = dir ? WhB : WhF;
  const float* bias = dir ? bB : bF;
  _Float16* hb = hbuf + (size_t)dir * (2 * B_ * H_);

  // load W slice (f32 -> f16) : lds col c = gate(c>>3)*1024 + cb*8 + (c&7)
  for (int idx = tid; idx < KTOT * 32; idx += 512) {
    int k = idx >> 5, c = idx & 31;
    int wcol = ((c >> 3) << 10) + cb * 8 + (c & 7);
    float v = (k < E_) ? Wx[k * G_ + wcol] : Wh[(k - E_) * G_ + wcol];
    Wlds[c][k] = (_Float16)v;
  }
  if (tid < 32)  bias_s[tid] = bias[((tid >> 3) << 10) + cb * 8 + (tid & 7)];
  if (tid < B_)  len_s[tid] = lengths[tid];
  __syncthreads();     // last wg-wide barrier: W/bias/len ready

  // gate-phase mapping: thread -> (batch gb, h-sub-cols gj, gj+1)
  const int gb = tid >> 2;
  const int gj = (tid & 3) * 2;
  float creg0 = 0.f, creg1 = 0.f, hreg0 = 0.f, hreg1 = 0.f;

  // GEMM mapping (wave-local rows)
  const int mrow = (wv << 4) + (lane & 15);   // batch row for A-frag
  const int ksub = (lane >> 4) << 3;          // k-offset within 32-block
  const int c0   = lane & 15;                 // B-frag column within N-tile
  const _Float16* xbase = x + (size_t)mrow * T_ * E_;
  const _Float16* w0 = &Wlds[c0][0];
  const _Float16* w1 = &Wlds[16 + c0][0];

  float hx0 = (float)(lane + 1), hx1 = 2.0f;   // heater state

  int cur = 0;
#pragma unroll 1
  for (int s = 0; s < T_; ++s) {
    const int t = dir ? (T_ - 1 - s) : s;

    // one-time midpoint: other dir's row-group w passed step 255 (its out
    // partials released via wbl2), so our RMW reads are L3-fresh.
    if (s == 256) {
      while (1) {
        unsigned a = __hip_atomic_load(fl_oth + lane,      __ATOMIC_RELAXED, __HIP_MEMORY_SCOPE_SYSTEM);
        unsigned b = __hip_atomic_load(fl_oth + 64 + lane, __ATOMIC_RELAXED, __HIP_MEMORY_SCOPE_SYSTEM);
        if (__all(a >= 256u && b >= 256u)) break;
        HEAT();
      }
      __builtin_amdgcn_fence(__ATOMIC_ACQUIRE, "agent");  // one-time inv (safety)
    }

    // prefetch out-RMW operands (stable post-midpoint), overlaps the flag wait
    float* op = out + ((size_t)gb * T_ + t) * H_ + cb * 8 + gj;
    float oy0 = 0.f, oy1 = 0.f;
    if (s >= 256) { oy0 = op[0]; oy1 = op[1]; }

    // x-part GEMM: no dependency on h(s-1), runs before the flag wait
    f32x4 acc0 = {0.f, 0.f, 0.f, 0.f}, acc1 = {0.f, 0.f, 0.f, 0.f};
    {
      const _Float16* xr = xbase + t * E_ + ksub;
#pragma unroll
      for (int kk = 0; kk < 8; ++kk) {       // k = 0..255
        f16x8 a  = *(const f16x8*)(xr + kk * 32);
        f16x8 q0 = *(const f16x8*)(w0 + ksub + kk * 32);
        f16x8 q1 = *(const f16x8*)(w1 + ksub + kk * 32);
        acc0 = __builtin_amdgcn_mfma_f32_16x16x32_f16(a, q0, acc0, 0, 0, 0);
        acc1 = __builtin_amdgcn_mfma_f32_16x16x32_f16(a, q1, acc1, 0, 0, 0);
      }
    }

    if (s > 0) {
      // wait: row-group w of all 128 wgs of this dir completed step s-1.
      // HOT poll (no s_sleep): FMA heater holds SCLK at boost.
      const unsigned tgt = (unsigned)s;
      while (1) {
        unsigned a = __hip_atomic_load(fl_own + lane,      __ATOMIC_RELAXED, __HIP_MEMORY_SCOPE_SYSTEM);
        unsigned b = __hip_atomic_load(fl_own + 64 + lane, __ATOMIC_RELAXED, __HIP_MEMORY_SCOPE_SYSTEM);
        if (__all(a >= tgt && b >= tgt)) break;
        HEAT();
      }

      // h-part GEMM, A-operands via L2-bypass loads (h written through to L3)
      const _Float16* hr = hb + (size_t)cur * (B_ * H_) + mrow * H_ + ksub;
      f16x8 ha[32];
      HLD(ha[0],  hr, "0");    HLD(ha[1],  hr, "64");   HLD(ha[2],  hr, "128");  HLD(ha[3],  hr, "192");
      HLD(ha[4],  hr, "256");  HLD(ha[5],  hr, "320");  HLD(ha[6],  hr, "384");  HLD(ha[7],  hr, "448");
      HLD(ha[8],  hr, "512");  HLD(ha[9],  hr, "576");  HLD(ha[10], hr, "640");  HLD(ha[11], hr, "704");
      HLD(ha[12], hr, "768");  HLD(ha[13], hr, "832");  HLD(ha[14], hr, "896");  HLD(ha[15], hr, "960");
      HLD(ha[16], hr, "1024"); HLD(ha[17], hr, "1088"); HLD(ha[18], hr, "1152"); HLD(ha[19], hr, "1216");
      HLD(ha[20], hr, "1280"); HLD(ha[21], hr, "1344"); HLD(ha[22], hr, "1408"); HLD(ha[23], hr, "1472");
      HLD(ha[24], hr, "1536"); HLD(ha[25], hr, "1600"); HLD(ha[26], hr, "1664"); HLD(ha[27], hr, "1728");
      HLD(ha[28], hr, "1792"); HLD(ha[29], hr, "1856"); HLD(ha[30], hr, "1920"); HLD(ha[31], hr, "1984");

      asm volatile("s_waitcnt vmcnt(16)" ::: "memory");  // chunk A landed
      __builtin_amdgcn_sched_barrier(0);
#pragma unroll
      for (int kk = 0; kk < 16; ++kk) {
        f16x8 q0 = *(const f16x8*)(w0 + E_ + ksub + kk * 32);
        f16x8 q1 = *(const f16x8*)(w1 + E_ + ksub + kk * 32);
        acc0 = __builtin_amdgcn_mfma_f32_16x16x32_f16(ha[kk], q0, acc0, 0, 0, 0);
        acc1 = __builtin_amdgcn_mfma_f32_16x16x32_f16(ha[kk], q1, acc1, 0, 0, 0);
      }
      asm volatile("s_waitcnt vmcnt(0)" ::: "memory");   // chunk B landed
      __builtin_amdgcn_sched_barrier(0);
#pragma unroll
      for (int kk = 16; kk < 32; ++kk) {
        f16x8 q0 = *(const f16x8*)(w0 + E_ + ksub + kk * 32);
        f16x8 q1 = *(const f16x8*)(w1 + E_ + ksub + kk * 32);
        acc0 = __builtin_amdgcn_mfma_f32_16x16x32_f16(ha[kk], q0, acc0, 0, 0, 0);
        acc1 = __builtin_amdgcn_mfma_f32_16x16x32_f16(ha[kk], q1, acc1, 0, 0, 0);
      }
    }

    // dump z tile to wave-private zlds rows. C layout: col=lane&15, row=(lane>>4)*4+r
    {
      int r0 = (wv << 4) + ((lane >> 4) << 2);
#pragma unroll
      for (int r = 0; r < 4; ++r) {
        zlds[r0 + r][c0]      = acc0[r];
        zlds[r0 + r][16 + c0] = acc1[r];
      }
    }
    // no barrier: zlds rows [16wv,16wv+16) written and read by the SAME wave
    {
      bool m = t < len_s[gb];
      float zi0 = zlds[gb][gj]      + bias_s[gj];
      float zf0 = zlds[gb][8 + gj]  + bias_s[8 + gj];
      float zg0 = zlds[gb][16 + gj] + bias_s[16 + gj];
      float zo0 = zlds[gb][24 + gj] + bias_s[24 + gj];
      float zi1 = zlds[gb][gj + 1]  + bias_s[gj + 1];
      float zf1 = zlds[gb][9 + gj]  + bias_s[9 + gj];
      float zg1 = zlds[gb][17 + gj] + bias_s[17 + gj];
      float zo1 = zlds[gb][25 + gj] + bias_s[25 + gj];

      float cn0 = sigm(zf0) * creg0 + sigm(zi0) * tanh_fast(zg0);
      float hn0 = sigm(zo0) * tanh_fast(cn0);
      float cn1 = sigm(zf1) * creg1 + sigm(zi1) * tanh_fast(zg1);
      float hn1 = sigm(zo1) * tanh_fast(cn1);
      if (m) { creg0 = cn0; hreg0 = hn0; creg1 = cn1; hreg1 = hn1; }
      float y0 = m ? hn0 : 0.f;
      float y1 = m ? hn1 : 0.f;

      // h write-through to the L3 coherence point (4B packed system store)
      _Float16* hw = hb + (size_t)(cur ^ 1) * (B_ * H_) + gb * H_ + cb * 8 + gj;
      union { _Float16 h2[2]; unsigned u; } pk;
      pk.h2[0] = (_Float16)hreg0; pk.h2[1] = (_Float16)hreg1;
      __hip_atomic_store((unsigned*)hw, pk.u, __ATOMIC_RELAXED, __HIP_MEMORY_SCOPE_SYSTEM);

      if (s < 256) {                         // first writer: raw partial sum
        op[0] = y0; op[1] = y1;
      } else {                               // second writer: add + fused output dropout
        unsigned i0 = (((unsigned)gb * T_ + (unsigned)t) << 10) + (unsigned)(cb * 8 + gj);
        float f0 = oy0 + y0, f1 = oy1 + y1;
        op[0] = jax_keep(2u, i0)      ? f0 * 1.25f : 0.f;
        op[1] = jax_keep(2u, i0 + 1u) ? f1 * 1.25f : 0.f;
      }
    }

    // publish: drain THIS wave's stores, then one flag store by lane 0.
    // s==255 publishes with RELEASE (wbl2) so the other dir sees out partials.
    if (s < T_ - 1) {
      asm volatile("s_waitcnt vmcnt(0)" ::: "memory");
      if (lane == 0) {
        if (s == 255)
          __hip_atomic_store(fl_own + cb, 256u, __ATOMIC_RELEASE, __HIP_MEMORY_SCOPE_SYSTEM);
        else
          __hip_atomic_store(fl_own + cb, (unsigned)(s + 1), __ATOMIC_RELAXED, __HIP_MEMORY_SCOPE_SYSTEM);
      }
    }
    cur ^= 1;
  }
}

extern "C" void kernel_launch(void* const* d_in, const int* in_sizes, int n_in,
                              void* d_out, int out_size, void* d_ws, size_t ws_size,
                              hipStream_t stream) {
  (void)in_sizes; (void)n_in; (void)out_size; (void)ws_size;
  const int*   tokens  = (const int*)d_in[0];
  const int*   lengths = (const int*)d_in[1];
  const float* emb     = (const float*)d_in[2];
  const float* WxF     = (const float*)d_in[3];
  const float* WhF     = (const float*)d_in[4];
  const float* bF      = (const float*)d_in[5];
  const float* WxB     = (const float*)d_in[6];
  const float* WhB     = (const float*)d_in[7];
  const float* bB      = (const float*)d_in[8];
  float* out = (float*)d_out;

  _Float16* x     = (_Float16*)d_ws;                                     // 32 MB
  _Float16* hbuf  = (_Float16*)((char*)d_ws + (size_t)B_ * T_ * E_ * 2); // 1 MB
  unsigned* flags = (unsigned*)((char*)d_ws + 34603008);                 // 8 KB

  hipMemsetAsync(flags, 0, 8192, stream);

  embed_kernel<<<(B_ * T_ * E_ + 255) / 256, 256, 0, stream>>>(tokens, lengths, emb, x);

  void* args[] = { (void*)&WxF, (void*)&WhF, (void*)&bF,
                   (void*)&WxB, (void*)&WhB, (void*)&bB,
                   (void*)&lengths, (void*)&x, (void*)&hbuf, (void*)&flags, (void*)&out };
  hipLaunchCooperativeKernel((const void*)lstm_kernel, dim3(256), dim3(512),
                             args, 0, stream);
}